// Round 10
// baseline (9843.391 us; speedup 1.0000x reference)
//
#include <hip/hip_runtime.h>
#include <stdint.h>

// LSTMClassifier: 2-layer LSTM (B=128,T=1024,I=256,H=512) + FC(512->1).
// Persistent grid-resident kernel. R15 = R14 cross-block protocol byte-for-byte
// (4-deep h rings, dataflow poll thresholds, relaxed SYSTEM-scope sc0 sc1
// atomics, wave0-only poll, own slot masked) + intra-block overlap:
//   - wave1 is the sole eltwise/store/drain/flag wave (4 outputs/lane,
//     c-state x4 in regs); flag posts right after ITS vmcnt(0) - no barrier.
//   - wave0 polls for step s+1 right after the dump barrier, overlapping
//     wave1's eltwise+store+drain (detect hides under produce tail).
//   - LDS tokens replace 2 of 3 barriers: tok[0]=ready (wave0 detect bcast),
//     tok[1]=consumed (red reads done -> gates ping-pong red redump),
//     tok[2]=drained (own h stores acked -> gates own next-step h loads,
//     preserving the own-tile visibility the deleted barrier provided).
//   - red buffer ping-pong red[2][4][16][68]; ONE barrier/step (dump ready).
// Chain/step: detect(overlapped) + load RT + MFMA + eltwise + drain RT +
// flag one-way  ~= 2.5-3 IF$ RTs vs R14's ~4.5 RTs + 3 barriers.
//
// ws layout (bytes):
//   Wp0 [2048][768]  bf16 packed rows r=u*4+q  (cols: 0..255=W_ih0, 256..767=W_hh0)
//   Wp1 [2048][1024] bf16 packed                (cols: 0..511=W_ih1, 512..1023=W_hh1)
//   bp0/bp1 [2048] f32 (b_ih+b_hh, packed order)
//   h    ushort[8][128*512]: h0 ring slots 0..3, then h1 ring slots 0..3
//   cnt  flag slots: 8 groups x 64 dwords (one single-writer slot per block)

#define T_STEPS 1024
#define NBLK 512
#define NTHR 256

#define WS_WP0   0u
#define WS_WP1   3145728u
#define WS_BP0   7340032u
#define WS_BP1   7348224u
#define WS_H     7356416u
#define WS_CNT   8404992u
#define CNT_U32  512         // 8 groups x 64 slots

typedef __bf16 bf16x8 __attribute__((ext_vector_type(8)));
typedef float  f32x4  __attribute__((ext_vector_type(4)));
typedef unsigned long long ull;
typedef ull u64x2 __attribute__((ext_vector_type(2)));

__device__ __forceinline__ unsigned short f2bf(float f) {
    union { float f; uint32_t u; } a; a.f = f;
    uint32_t r = a.u + 0x7fffu + ((a.u >> 16) & 1u);
    return (unsigned short)(r >> 16);
}
__device__ __forceinline__ float bf2f(unsigned short u) {
    union { uint32_t u; float f; } a; a.u = ((uint32_t)u) << 16; return a.f;
}
__device__ __forceinline__ float sigm(float x)  { return 1.f / (1.f + __expf(-x)); }
__device__ __forceinline__ float tanh_f(float x){ return 2.f / (1.f + __expf(-2.f * x)) - 1.f; }

// IF$-coherent (L1+L2-bypassing) accessors: relaxed system atomics -> sc0 sc1
__device__ __forceinline__ bf16x8 ld_h16(const unsigned short* p) {
    u64x2 t;
    t.x = __hip_atomic_load((const ull*)p,       __ATOMIC_RELAXED, __HIP_MEMORY_SCOPE_SYSTEM);
    t.y = __hip_atomic_load((const ull*)(p + 4), __ATOMIC_RELAXED, __HIP_MEMORY_SCOPE_SYSTEM);
    return __builtin_bit_cast(bf16x8, t);
}
__device__ __forceinline__ void st_sys_u32(unsigned* p, unsigned v) {
    __hip_atomic_store(p, v, __ATOMIC_RELAXED, __HIP_MEMORY_SCOPE_SYSTEM);
}
__device__ __forceinline__ unsigned ld_sys_u32(const unsigned* p) {
    return __hip_atomic_load(p, __ATOMIC_RELAXED, __HIP_MEMORY_SCOPE_SYSTEM);
}

// ---- pre-pack weights to bf16, gate-interleaved rows r = u*4 + q (q: i,f,g,o) ----
__global__ void k_pack(const float* __restrict__ Wih0, const float* __restrict__ Whh0,
                       const float* __restrict__ Wih1, const float* __restrict__ Whh1,
                       unsigned short* __restrict__ Wp0, unsigned short* __restrict__ Wp1)
{
    int t = blockIdx.x * blockDim.x + threadIdx.x;
    const int N0 = 2048 * 768;
    const int N1 = 2048 * 1024;
    if (t < N0) {
        int r = t / 768, k = t - r * 768;
        int u = r >> 2, q = r & 3, row = q * 512 + u;
        float v = (k < 256) ? Wih0[row * 256 + k] : Whh0[row * 512 + (k - 256)];
        Wp0[t] = f2bf(v);
    } else if (t < N0 + N1) {
        int t2 = t - N0;
        int r = t2 >> 10, k = t2 & 1023;
        int u = r >> 2, q = r & 3, row = q * 512 + u;
        float v = (k < 512) ? Wih1[row * 512 + k] : Whh1[row * 512 + (k - 512)];
        Wp1[t2] = f2bf(v);
    }
}

// ---- biases (packed), zero h ring buffers, zero flag slots ----
__global__ void k_misc(const float* __restrict__ bih0, const float* __restrict__ bhh0,
                       const float* __restrict__ bih1, const float* __restrict__ bhh1,
                       float* __restrict__ bp0, float* __restrict__ bp1,
                       unsigned short* __restrict__ hbufs, unsigned* __restrict__ cnt)
{
    int t = blockIdx.x * blockDim.x + threadIdx.x;
    if (t < 2048) {
        int u = t >> 2, q = t & 3, row = q * 512 + u;
        bp0[t] = bih0[row] + bhh0[row];
    } else if (t < 4096) {
        int r = t - 2048; int u = r >> 2, q = r & 3, row = q * 512 + u;
        bp1[r] = bih1[row] + bhh1[row];
    } else if (t < 4096 + 524288) {
        hbufs[t - 4096] = 0;
    } else if (t < 4096 + 524288 + CNT_U32) {
        cnt[t - (4096 + 524288)] = 0;
    }
}

// ---- persistent LSTM ----
// NKW: ksteps per wave; KTOT: total K; KS: boundary src0/src1; L0: layer-0 flag
// h rings: h0(t) at hb + (t&3)*65536, h1(t) at hb + 262144 + (t&3)*65536
template<int NKW, int KTOT, int KS, bool L0>
__device__ __forceinline__ void run_layer(
    int b0, int ut0, int g0, int w, int col, int quad, int tid,
    const float* __restrict__ x,
    const unsigned short* __restrict__ Wp,
    const float* __restrict__ bp,
    unsigned short* __restrict__ hb,
    unsigned* slots, int myslot,
    float (*red)[4][16][68], volatile int* tok)
{
    const int bA   = b0 + col;  // A-fragment row (batch index)
    const int lane = tid & 63;

    // B fragments (weights) -> register-resident for the whole run (pinned).
    uint4 Bf[4][NKW];
    #pragma unroll
    for (int f = 0; f < 4; ++f) {
        const unsigned short* wrow = Wp + (g0 + f * 16 + col) * KTOT + w * (NKW * 32) + quad * 8;
        #pragma unroll
        for (int ks = 0; ks < NKW; ++ks)
            Bf[f][ks] = *(const uint4*)(wrow + ks * 32);
    }
    #pragma unroll
    for (int f = 0; f < 4; ++f) {
        #pragma unroll
        for (int ks = 0; ks < NKW; ++ks) {
            uint32_t c0 = Bf[f][ks].x, c1 = Bf[f][ks].y, c2 = Bf[f][ks].z, c3 = Bf[f][ks].w;
            asm volatile("" : "+v"(c0), "+v"(c1), "+v"(c2), "+v"(c3));
            Bf[f][ks].x = c0; Bf[f][ks].y = c1; Bf[f][ks].z = c2; Bf[f][ks].w = c3;
        }
    }

    // wave1 eltwise domain: lane -> unit ul = lane&15; batches bl = (lane>>4)+4k
    const int ul = lane & 15;
    const f32x4 bias4 = *(const f32x4*)(bp + g0 + ul * 4);
    float cst[4] = {0.f, 0.f, 0.f, 0.f};        // cell state (wave1 only uses)

    // Per-kstep A source offsets (frag never straddles the KS boundary: 32 | KS)
    int  offA[NKW];
    bool s0[NKW];
    #pragma unroll
    for (int ks = 0; ks < NKW; ++ks) {
        int kg = w * (NKW * 32) + ks * 32 + quad * 8;
        if (kg < KS) { s0[ks] = true;  offA[ks] = L0 ? (bA * (T_STEPS * 256) + kg) : (bA * 512 + kg); }
        else         { s0[ks] = false; offA[ks] = bA * 512 + (kg - KS); }
    }

    // SMAX: l0 computes s=0..T-1; l1 computes h1(s-1) for s=1..T
    const int SMAX = L0 ? (T_STEPS - 1) : T_STEPS;

    for (int s = 0; s <= SMAX; ++s) {
        const bool active = L0 || (s >= 1);
        bf16x8 Af[NKW];

        if (L0) {
            // x-part first: static data, overlaps the spin/detect window
            const float* xb = x + s * 256;
            #pragma unroll
            for (int ks = 0; ks < NKW; ++ks) {
                if (s0[ks]) {
                    const float* p = xb + offA[ks];
                    float4 lo = *(const float4*)p;
                    float4 hi = *(const float4*)(p + 4);
                    bf16x8 v;
                    v[0]=(__bf16)lo.x; v[1]=(__bf16)lo.y; v[2]=(__bf16)lo.z; v[3]=(__bf16)lo.w;
                    v[4]=(__bf16)hi.x; v[5]=(__bf16)hi.y; v[6]=(__bf16)hi.z; v[7]=(__bf16)hi.w;
                    Af[ks] = v;
                }
            }
        }

        // readiness: wave0 detects cross-block deps (often pre-overlapped with
        // previous step's produce tail), broadcasts via tok[0]. tok[2] gates on
        // own stores drained (own slot is masked in the poll).
        if (w == 0) {
            if (s >= 1) {
                int tgt = L0 ? (s - ((lane & 1) << 1)) : s;   // l0: l0>=s, l1>=s-2 ; l1: all>=s
                if (lane == myslot) tgt = (int)0x80000000;
                for (;;) {
                    int v = (int)ld_sys_u32(slots + lane);
                    if (__all(v >= tgt)) break;
                    __builtin_amdgcn_s_sleep(1);
                }
            }
            if (lane == 0) tok[0] = s;
            while (tok[2] < s - 1) { }
        } else {
            while (tok[0] < s || tok[2] < s - 1) { }
        }
        asm volatile("" ::: "memory");

        if (active) {
            if (L0) {
                const unsigned short* hr = hb + (((unsigned)(s + 3)) & 3u) * 65536; // h0(s-1)
                #pragma unroll
                for (int ks = 0; ks < NKW; ++ks)
                    if (!s0[ks]) Af[ks] = ld_h16(hr + offA[ks]);
            } else {
                const unsigned short* h0r = hb + (((unsigned)(s + 3)) & 3u) * 65536;           // h0(s-1)
                const unsigned short* h1r = hb + 262144 + (((unsigned)(s + 2)) & 3u) * 65536;  // h1(s-2)
                #pragma unroll
                for (int ks = 0; ks < NKW; ++ks)
                    Af[ks] = ld_h16((s0[ks] ? h0r : h1r) + offA[ks]);
            }

            f32x4 acc[4] = { f32x4{0,0,0,0}, f32x4{0,0,0,0}, f32x4{0,0,0,0}, f32x4{0,0,0,0} };
            #pragma unroll
            for (int ks = 0; ks < NKW; ++ks) {
                #pragma unroll
                for (int f = 0; f < 4; ++f)
                    acc[f] = __builtin_amdgcn_mfma_f32_16x16x32_bf16(
                        Af[ks], __builtin_bit_cast(bf16x8, Bf[f][ks]), acc[f], 0, 0, 0);
            }
            // red ping-pong: wait until wave1 consumed buffer (s-2), then dump
            while (tok[1] < s - 2) { }
            asm volatile("" ::: "memory");
            #pragma unroll
            for (int f = 0; f < 4; ++f) {
                #pragma unroll
                for (int r = 0; r < 4; ++r)
                    red[s & 1][w][quad * 4 + r][f * 16 + col] = acc[f][r];
            }
        }
        __syncthreads();   // dump complete (single barrier per step)

        if (w == 1) {
            if (active) {
                unsigned pk[4];
                #pragma unroll
                for (int k = 0; k < 4; ++k) {
                    const int bl = (lane >> 4) + 4 * k;
                    f32x4 g = bias4;
                    #pragma unroll
                    for (int ww = 0; ww < 4; ++ww)
                        g += *(const f32x4*)&red[s & 1][ww][bl][ul * 4];
                    float ig = sigm(g[0]), fg = sigm(g[1]), gc = tanh_f(g[2]), og = sigm(g[3]);
                    cst[k] = fg * cst[k] + ig * gc;
                    float h = og * tanh_f(cst[k]);
                    unsigned hv = (unsigned)f2bf(h);
                    unsigned pv = (unsigned)__shfl_xor((int)hv, 1);
                    pk[k] = hv | (pv << 16);
                }
                if (lane == 0) tok[1] = s;    // red consumed (reads done above)
                unsigned short* hw = L0
                    ? (hb + (((unsigned)s) & 3u) * 65536)                       // h0(s)
                    : (hb + 262144 + (((unsigned)(s + 3)) & 3u) * 65536);       // h1(s-1)
                if (!(ul & 1)) {
                    #pragma unroll
                    for (int k = 0; k < 4; ++k) {
                        const int bl = (lane >> 4) + 4 * k;
                        st_sys_u32((unsigned*)(hw + (b0 + bl) * 512 + ut0 + ul), pk[k]);
                    }
                }
                asm volatile("s_waitcnt vmcnt(0)" ::: "memory");   // drain own h stores
            }
            if (lane == 0) { tok[2] = s; }                          // own drain done
            if (lane == 0) st_sys_u32(slots + myslot, (unsigned)(s + 1));  // post flag
        }
        // no trailing barrier: next-iter gates are tok[0]/tok[1]/tok[2]
    }
}

__global__ __launch_bounds__(NTHR, 2) void lstm_persistent(
    const float* __restrict__ x,
    const unsigned short* __restrict__ Wp0, const unsigned short* __restrict__ Wp1,
    const float* __restrict__ bp0, const float* __restrict__ bp1,
    unsigned short* __restrict__ hb, unsigned* __restrict__ cnt)
{
    __shared__ alignas(16) float red[2][4][16][68];   // ping-pong reduction buffer
    __shared__ int tokbuf[4];
    const int bid   = blockIdx.x;
    const int g     = bid & 7;          // batch-tile group (independent flag domain)
    const int rest  = bid >> 3;         // 0..63: pid within group
    const int layer = rest & 1;
    const int ut    = rest >> 1;        // 0..31 unit-tile
    const int b0    = g * 16;
    const int ut0   = ut * 16;
    const int g0    = ut * 64;          // packed gate-row base (= ut0*4)
    const int tid   = threadIdx.x;
    const int w = tid >> 6, lane = tid & 63, col = lane & 15, quad = lane >> 4;

    if (tid == 0) { tokbuf[0] = -1; tokbuf[1] = -1; tokbuf[2] = -1; tokbuf[3] = 0; }
    __syncthreads();
    volatile int* tok = tokbuf;

    unsigned* slots = cnt + g * 64;
    const int myslot = rest;

    if (layer == 0)
        run_layer<6, 768, 256, true >(b0, ut0, g0, w, col, quad, tid, x, Wp0, bp0, hb, slots, myslot, red, tok);
    else
        run_layer<8, 1024, 512, false>(b0, ut0, g0, w, col, quad, tid, x, Wp1, bp1, hb, slots, myslot, red, tok);
}

// ---- final FC head: logits[b] = h1_T[b,:] . fc_w + fc_b ----
// final h1(1023) lives in h1 ring slot 1023&3 = 3
__global__ void k_fc(const unsigned short* __restrict__ h1, const float* __restrict__ fcw,
                     const float* __restrict__ fcb, float* __restrict__ out)
{
    int b = threadIdx.x;
    if (b < 128) {
        const unsigned short* hr = h1 + b * 512;
        float acc = 0.f;
        for (int u = 0; u < 512; ++u) acc += bf2f(hr[u]) * fcw[u];
        out[b] = acc + fcb[0];
    }
}

extern "C" void kernel_launch(void* const* d_in, const int* in_sizes, int n_in,
                              void* d_out, int out_size, void* d_ws, size_t ws_size,
                              hipStream_t stream)
{
    const float* x    = (const float*)d_in[0];
    const float* Wih0 = (const float*)d_in[1];
    const float* Whh0 = (const float*)d_in[2];
    const float* bih0 = (const float*)d_in[3];
    const float* bhh0 = (const float*)d_in[4];
    const float* Wih1 = (const float*)d_in[5];
    const float* Whh1 = (const float*)d_in[6];
    const float* bih1 = (const float*)d_in[7];
    const float* bhh1 = (const float*)d_in[8];
    const float* fcw  = (const float*)d_in[9];
    const float* fcb  = (const float*)d_in[10];

    char* ws = (char*)d_ws;
    unsigned short* Wp0 = (unsigned short*)(ws + WS_WP0);
    unsigned short* Wp1 = (unsigned short*)(ws + WS_WP1);
    float* bp0 = (float*)(ws + WS_BP0);
    float* bp1 = (float*)(ws + WS_BP1);
    unsigned short* hb = (unsigned short*)(ws + WS_H);
    unsigned* cnt = (unsigned*)(ws + WS_CNT);

    const int npack = 2048 * 768 + 2048 * 1024;
    k_pack<<<(npack + 255) / 256, 256, 0, stream>>>(Wih0, Whh0, Wih1, Whh1, Wp0, Wp1);
    const int nmisc = 4096 + 524288 + CNT_U32;
    k_misc<<<(nmisc + 255) / 256, 256, 0, stream>>>(bih0, bhh0, bih1, bhh1, bp0, bp1, hb, cnt);

    lstm_persistent<<<NBLK, NTHR, 0, stream>>>(x, Wp0, Wp1, bp0, bp1, hb, cnt);

    // final h1(1023) is in h1 ring slot 3: hb + 262144 + 3*65536
    k_fc<<<1, 128, 0, stream>>>(hb + 262144 + 196608, fcw, fcb, (float*)d_out);
}